// Round 1
// baseline (207.274 us; speedup 1.0000x reference)
//
#include <hip/hip_runtime.h>

// Bottom-up HTMM forward log-likelihood on a complete 4-ary tree, depth 7.
// Tree structure is deterministic: children(u) = 4u+1..4u+4, pos(u) = (u-1)&3.
// Only labels t[u*7+0] are data-dependent.

#define G 16
#define C 8
#define L 4
#define M 256
#define TSIZE 21845
#define SL 5461          // number of internal nodes == first leaf index
#define GC (G*C)         // 128

__device__ __forceinline__ float grp8_sum(float v) {
  v += __shfl_xor(v, 1);
  v += __shfl_xor(v, 2);
  v += __shfl_xor(v, 4);
  return v;
}

// ---------------- setup: softmaxes + logs ----------------
__global__ void setup_kernel(const float* __restrict__ ain, const float* __restrict__ bin,
                             const float* __restrict__ piin, const float* __restrict__ spin,
                             float* __restrict__ a_sp, float* __restrict__ log_a,
                             float* __restrict__ sm_b, float* __restrict__ log_b,
                             float* __restrict__ sm_pi, float* __restrict__ log_pi,
                             float* __restrict__ log_sp) {
  int blk = blockIdx.x, tid = threadIdx.x;
  if (blk < 16) {
    // softmax over labels (M=256) for b[g][c][:]
    int g = blk;
    __shared__ float red4[4];
    for (int c = 0; c < 8; ++c) {
      int row = g * 8 + c;
      float x = bin[row * 256 + tid];
      float m = x;
      #pragma unroll
      for (int off2 = 32; off2; off2 >>= 1) m = fmaxf(m, __shfl_xor(m, off2));
      if ((tid & 63) == 0) red4[tid >> 6] = m;
      __syncthreads();
      m = fmaxf(fmaxf(red4[0], red4[1]), fmaxf(red4[2], red4[3]));
      __syncthreads();
      float e = expf(x - m);
      float ssum = e;
      #pragma unroll
      for (int off2 = 32; off2; off2 >>= 1) ssum += __shfl_xor(ssum, off2);
      if ((tid & 63) == 0) red4[tid >> 6] = ssum;
      __syncthreads();
      ssum = red4[0] + red4[1] + red4[2] + red4[3];
      __syncthreads();
      sm_b[row * 256 + tid] = e / ssum;
      log_b[row * 256 + tid] = (x - m) - logf(ssum);
    }
  } else if (blk == 16) {
    // softmax of a over i (axis=1), times sm_sp -> a_sp; also log(sm_a)
    for (int col = tid; col < 512; col += 256) {
      int g = col >> 5, j = (col >> 2) & 7, l = col & 3;
      float x[8], m = -1e30f;
      #pragma unroll
      for (int i = 0; i < 8; ++i) { x[i] = ain[g*256 + i*32 + j*4 + l]; m = fmaxf(m, x[i]); }
      float ssum = 0.f;
      #pragma unroll
      for (int i = 0; i < 8; ++i) ssum += expf(x[i] - m);
      float ls = logf(ssum);
      // sm_sp[g][l] computed locally (avoids cross-block dependency)
      float y0 = spin[g*4+0], y1 = spin[g*4+1], y2 = spin[g*4+2], y3 = spin[g*4+3];
      float ms = fmaxf(fmaxf(y0, y1), fmaxf(y2, y3));
      float d = expf(y0-ms) + expf(y1-ms) + expf(y2-ms) + expf(y3-ms);
      float spv = expf(spin[g*4+l] - ms) / d;
      #pragma unroll
      for (int i = 0; i < 8; ++i) {
        int o2 = g*256 + i*32 + j*4 + l;
        float smv = expf(x[i] - m) / ssum;
        a_sp[o2]  = smv * spv;
        log_a[o2] = (x[i] - m) - ls;
      }
    }
  } else {
    if (tid < 64) {
      // softmax of pi over c (axis=1) for each (g,l)
      int g = tid >> 2, l = tid & 3;
      float x[8], m = -1e30f;
      #pragma unroll
      for (int c = 0; c < 8; ++c) { x[c] = piin[g*32 + c*4 + l]; m = fmaxf(m, x[c]); }
      float ssum = 0.f;
      #pragma unroll
      for (int c = 0; c < 8; ++c) ssum += expf(x[c] - m);
      float ls = logf(ssum);
      #pragma unroll
      for (int c = 0; c < 8; ++c) {
        int o2 = g*32 + c*4 + l;
        sm_pi[o2]  = expf(x[c] - m) / ssum;
        log_pi[o2] = (x[c] - m) - ls;
      }
    } else if (tid < 80) {
      // log softmax of sp over l
      int g = tid - 64;
      float y[4], m = -1e30f;
      #pragma unroll
      for (int l = 0; l < 4; ++l) { y[l] = spin[g*4 + l]; m = fmaxf(m, y[l]); }
      float ssum = 0.f;
      #pragma unroll
      for (int l = 0; l < 4; ++l) ssum += expf(y[l] - m);
      float ls = logf(ssum);
      #pragma unroll
      for (int l = 0; l < 4; ++l) log_sp[g*4 + l] = (y[l] - m) - ls;
    }
  }
}

// ---------------- leaves: prior + beta ----------------
__global__ void leaf_kernel(const int* __restrict__ t, const float* __restrict__ sm_pi,
                            const float* __restrict__ sm_b, float* __restrict__ prior,
                            float* __restrict__ beta) {
  int idx = blockIdx.x * 256 + threadIdx.x;   // exactly 16384*128 threads
  int c = idx & 7, g = (idx >> 3) & 15, p = idx >> 7;
  int u = SL + p;
  int lab = t[u * 7];
  int pos = (u - 1) & 3;
  float pr = sm_pi[g*32 + c*4 + pos];
  float em = sm_b[g*2048 + c*256 + lab];
  float bt = pr * em;
  float ssum = grp8_sum(bt);
  size_t o = (size_t)u * GC + g * C + c;
  prior[o] = pr;
  beta[o]  = bt / ssum;
}

// ---------------- upward: one level ----------------
// thread = (node p, g, i): u_prior/u_beta_num over children (j,l)
__global__ void up_kernel(const float* __restrict__ a_sp, const float* __restrict__ sm_b,
                          const int* __restrict__ t, float* __restrict__ prior,
                          float* __restrict__ beta, float* __restrict__ numbeta,
                          float* __restrict__ eps, int s, int n) {
  int idx = blockIdx.x * 256 + threadIdx.x;
  if (idx >= n * GC) return;
  int i = idx & 7, g = (idx >> 3) & 15, p = idx >> 7;
  int u = s + p;
  const float* asp = a_sp + g*256 + i*32;
  float up = 0.f, ub = 0.f;
  int ch0 = 4*u + 1;
  #pragma unroll
  for (int l = 0; l < 4; ++l) {
    const float* pch = prior + (size_t)(ch0 + l) * GC + g * C;
    const float* bch = beta  + (size_t)(ch0 + l) * GC + g * C;
    #pragma unroll
    for (int j = 0; j < 8; ++j) {
      float wv = asp[j*4 + l];
      up += wv * pch[j];
      ub += wv * bch[j];
    }
  }
  int lab = t[u * 7];
  float emis = sm_b[g*2048 + i*256 + lab];
  float tmp = emis * ub;                // emis * u_bil * u_prior
  float ssum = grp8_sum(tmp);
  size_t o = (size_t)u * GC + g * C + i;
  float ubeta = tmp / ssum;
  prior[o]   = up;
  beta[o]    = ubeta;
  numbeta[o] = ub;                      // = prior * beta_il
  if (s == 0) eps[o] = ubeta;           // eps_i[root] = beta[root]
}

// ---------------- downward: one level ----------------
// thread = (node p, g, i=PARENT state).
// Reference quirk: child_eps sums over child state j, indexed by parent state i:
//   eps[ch_l][g,i] = pe[i] * sum_j a_sp[g,i,j,l] * beta[ch_l][g,j]
// Accumulate a_lh + sp_lh contributions per (u,g) into contrib (no eps_ijl storage).
__global__ void down_kernel(const float* __restrict__ a_sp, const float* __restrict__ log_a,
                            const float* __restrict__ log_sp, const float* __restrict__ numbeta,
                            const float* __restrict__ beta, float* __restrict__ eps,
                            float* __restrict__ contrib, int s, int n) {
  int idx = blockIdx.x * 256 + threadIdx.x;
  if (idx >= n * GC) return;
  int i = idx & 7, g = (idx >> 3) & 15, p = idx >> 7;
  int u = s + p;
  size_t o = (size_t)u * GC + g * C + i;
  float pe = eps[o] / numbeta[o];
  const float* aspgi = a_sp  + g*256 + i*32;
  const float* lagi  = log_a + g*256 + i*32;
  float local = 0.f;
  int ch0 = 4*u + 1;
  #pragma unroll
  for (int l = 0; l < 4; ++l) {
    const float* bch = beta + (size_t)(ch0 + l) * GC + g * C;
    float S = 0.f, A = 0.f;
    #pragma unroll
    for (int j = 0; j < 8; ++j) {
      float wv = aspgi[j*4 + l];
      float bj = bch[j];
      S += wv * bj;
      A += wv * lagi[j*4 + l] * bj;
    }
    float ce = pe * S;                         // sum_j res[i,j,l]
    eps[(size_t)(ch0 + l) * GC + g * C + i] = ce;
    local += pe * A + ce * log_sp[g*4 + l];    // a_lh + sp_lh parts
  }
  local = grp8_sum(local);
  if (i == 0) contrib[(size_t)u * G + g] = local;
}

// ---------------- final reduction, stage 1 ----------------
// b_lh over all nodes, pi_lh over leaves, + contrib (a_lh+sp_lh) for internal.
__global__ void final1_kernel(const int* __restrict__ t, const float* __restrict__ log_b,
                              const float* __restrict__ log_pi, const float* __restrict__ eps,
                              const float* __restrict__ contrib, double* __restrict__ partial) {
  int tid = threadIdx.x;
  int c = tid & 7, g = (tid >> 3) & 15;
  int slot = blockIdx.x * 2 + (tid >> 7);      // 1024 slots striding over u
  double acc = 0.0;
  for (int u = slot; u < TSIZE; u += 1024) {
    int lab = t[u * 7];
    float e = eps[(size_t)u * GC + g * C + c];
    float term = e * log_b[g*2048 + c*256 + lab];
    if (u >= SL) term += e * log_pi[g*32 + c*4 + ((u - 1) & 3)];
    acc += (double)term;
    if (u < SL && c == 0) acc += (double)contrib[(size_t)u * G + g];
  }
  acc += __shfl_xor(acc, 1);
  acc += __shfl_xor(acc, 2);
  acc += __shfl_xor(acc, 4);
  __shared__ double sd[32];
  if (c == 0) sd[(tid >> 7) * 16 + g] = acc;
  __syncthreads();
  if (tid < 16) partial[(size_t)blockIdx.x * 16 + tid] = sd[tid] + sd[16 + tid];
}

// ---------------- final reduction, stage 2 ----------------
__global__ void final2_kernel(const double* __restrict__ partial, float* __restrict__ out) {
  int tid = threadIdx.x;          // 256 = 16 g * 16 slots
  int g = tid >> 4, slot = tid & 15;
  double acc = 0.0;
  for (int bb = slot; bb < 512; bb += 16) acc += partial[(size_t)bb * 16 + g];
  acc += __shfl_xor(acc, 1);
  acc += __shfl_xor(acc, 2);
  acc += __shfl_xor(acc, 4);
  acc += __shfl_xor(acc, 8);
  if (slot == 0) out[g] = (float)acc;
}

extern "C" void kernel_launch(void* const* d_in, const int* in_sizes, int n_in,
                              void* d_out, int out_size, void* d_ws, size_t ws_size,
                              hipStream_t stream) {
  const int*   t  = (const int*)d_in[0];
  // d_in[1] = t_limits (unused; tree shape is compile-time constant)
  const float* a  = (const float*)d_in[2];
  const float* b  = (const float*)d_in[3];
  const float* pi = (const float*)d_in[4];
  const float* sp = (const float*)d_in[5];
  float* out = (float*)d_out;

  char* w = (char*)d_ws;
  size_t off = 0;
  auto carve = [&](size_t bytes) -> void* {
    void* p = w + off;
    off += (bytes + 255) & ~(size_t)255;
    return p;
  };
  float*  a_sp    = (float*)carve((size_t)G*C*C*L*4);
  float*  log_a   = (float*)carve((size_t)G*C*C*L*4);
  float*  sm_b    = (float*)carve((size_t)G*C*M*4);
  float*  log_b   = (float*)carve((size_t)G*C*M*4);
  float*  sm_pi   = (float*)carve((size_t)G*C*L*4);
  float*  log_pi  = (float*)carve((size_t)G*C*L*4);
  float*  log_sp  = (float*)carve((size_t)G*L*4);
  float*  prior   = (float*)carve((size_t)TSIZE*GC*4);
  float*  beta    = (float*)carve((size_t)TSIZE*GC*4);
  float*  eps     = (float*)carve((size_t)TSIZE*GC*4);
  float*  numbeta = (float*)carve((size_t)SL*GC*4);
  float*  contrib = (float*)carve((size_t)SL*G*4);
  double* partial = (double*)carve((size_t)512*G*8);
  // total ~38 MB of d_ws

  static const int lim[9] = {0, 1, 5, 21, 85, 341, 1365, 5461, 21845};

  setup_kernel<<<18, 256, 0, stream>>>(a, b, pi, sp, a_sp, log_a, sm_b, log_b,
                                       sm_pi, log_pi, log_sp);
  leaf_kernel<<<8192, 256, 0, stream>>>(t, sm_pi, sm_b, prior, beta);

  for (int lev = 6; lev >= 0; --lev) {
    int s = lim[lev], n = lim[lev + 1] - lim[lev];
    int blocks = (n * GC + 255) / 256;
    up_kernel<<<blocks, 256, 0, stream>>>(a_sp, sm_b, t, prior, beta, numbeta, eps, s, n);
  }
  for (int lev = 0; lev <= 6; ++lev) {
    int s = lim[lev], n = lim[lev + 1] - lim[lev];
    int blocks = (n * GC + 255) / 256;
    down_kernel<<<blocks, 256, 0, stream>>>(a_sp, log_a, log_sp, numbeta, beta, eps,
                                            contrib, s, n);
  }
  final1_kernel<<<512, 256, 0, stream>>>(t, log_b, log_pi, eps, contrib, partial);
  final2_kernel<<<1, 256, 0, stream>>>(partial, out);
}